// Round 8
// baseline (176.426 us; speedup 1.0000x reference)
//
#include <hip/hip_runtime.h>

typedef unsigned short USH;
typedef unsigned int UIN;
typedef _Float16 F16;
typedef F16 h2 __attribute__((ext_vector_type(2)));
typedef short bfrag __attribute__((ext_vector_type(8)));   // 8 bf16 (4 VGPR)
typedef float f32x4 __attribute__((ext_vector_type(4)));

__device__ __forceinline__ float bf2f(USH u) {
    return __uint_as_float(((unsigned int)u) << 16);
}
__device__ __forceinline__ USH f2bf(float f) {
    unsigned int i = __float_as_uint(f);
    i += 0x7FFFu + ((i >> 16) & 1u);   // RNE; values are finite
    return (USH)(i >> 16);
}
__device__ __forceinline__ UIN pkh2(float a, float b) {   // 2x f32 -> packed f16 (RNE)
    h2 h; h.x = (F16)a; h.y = (F16)b;
    return __builtin_bit_cast(UIN, h);
}
__device__ __forceinline__ h2 u2h(UIN u) { return __builtin_bit_cast(h2, u); }
__device__ __forceinline__ h2 relu2h(h2 s) {
    const h2 zz = {(F16)0.0f, (F16)0.0f};
    return __builtin_elementwise_max(s, zz);
}
__device__ __forceinline__ float fdot2(h2 a, h2 b, float c) {
#if __has_builtin(__builtin_amdgcn_fdot2)
    return __builtin_amdgcn_fdot2(a, b, c, false);
#else
    return c + (float)a.x * (float)b.x + (float)a.y * (float)b.y;
#endif
}

// flag: 1 = global inputs are bf16, 0 = f32
__device__ __forceinline__ float ldf(const void* p, long idx, int bf) {
    return bf ? bf2f(((const USH*)p)[idx]) : ((const float*)p)[idx];
}
__device__ __forceinline__ void ld4(const void* p, long idx, int bf, float o[4]) {
    if (bf) {
        ushort4 u = *(const ushort4*)((const USH*)p + idx);
        o[0] = bf2f(u.x); o[1] = bf2f(u.y); o[2] = bf2f(u.z); o[3] = bf2f(u.w);
    } else {
        float4 v = *(const float4*)((const float*)p + idx);
        o[0] = v.x; o[1] = v.y; o[2] = v.z; o[3] = v.w;
    }
}
// 8 consecutive E elements starting at element idx, as a bf16 MFMA fragment.
__device__ __forceinline__ bfrag ldfragE(const void* E, long idx, int bf) {
    if (bf) {
        return __builtin_bit_cast(bfrag, *(const uint4*)((const USH*)E + idx));
    } else {
        const float4 va = *(const float4*)((const float*)E + idx);
        const float4 vb = *(const float4*)((const float*)E + idx + 4);
        bfrag r;
        r[0] = (short)f2bf(va.x); r[1] = (short)f2bf(va.y);
        r[2] = (short)f2bf(va.z); r[3] = (short)f2bf(va.w);
        r[4] = (short)f2bf(vb.x); r[5] = (short)f2bf(vb.y);
        r[6] = (short)f2bf(vb.z); r[7] = (short)f2bf(vb.w);
        return r;
    }
}

// dtype detect from Ind (U(0,1) values). bf16: every ushort < 0x8000.
__device__ __forceinline__ int detect_bf(const void* ind) {
    const uint4* p = (const uint4*)ind;
    unsigned o = 0;
    #pragma unroll
    for (int i = 0; i < 8; ++i) { uint4 v = p[i]; o |= v.x | v.y | v.z | v.w; }
    return (o & 0x8000u) == 0;
}

// ---------------------------------------------------------------------------
// LEDGER (hardware-observed):
//  * per-t global partial writes: 76x HBM read amplification (banned).
//  * wave-uniform GLOBAL inner-loop operands (per-cp): waitcnt serialization
//    (banned). Per-t / per-k prefetch loads are fine.
//  * phantom WRITE_SIZE >> 16 MB == scratch spill. Guard: WRITE ~= 16 MB.
//  * R6: smaller tile did not raise occupancy; R7: barrier-free 1-wave blocks
//    ~= R5 (60 vs 61 us). k_main is issue-mix-limited, not sync-limited.
//  * Residue (total - k_main) ~= 100-110 us across ALL k_pre_d variants ->
//    ~90 us is harness-fixed; only k_pre_d width + k_main traffic are ours.
// R8: DELETE Dm. Epilogue computes each 16x16 D_k tile by MFMA from E
// directly (frag code HW-validated in R3-R5; D symmetric => transpose-safe;
// f32 accum = better precision than bf16 Dm). k_pre_d shrinks to 288 blocks.
// Lane mapping: n0=(lane>>4)*4 (4 rows), m0=lane&15 (1 col) == MFMA C layout.
// ---------------------------------------------------------------------------

// ---------------------------------------------------------------------------
// Kernel 1 (288 blocks): h-buffers only (f16 pairs, [9][32 cp][1024 row],
// plane 8 = W1s/section-B tile). Body identical to R5/R7's h-part.
// ---------------------------------------------------------------------------
__global__ __launch_bounds__(256) void k_pre_d(
    const void* __restrict__ x,    // [1024][8][64]
    const void* __restrict__ W1m,  // [128][64]
    const void* __restrict__ b1m,  // [64]
    const void* __restrict__ W1s,  // [128][64]
    const void* __restrict__ b1s,  // [64]
    const void* __restrict__ IndDet,
    UIN* __restrict__ hA16,        // [9][32][1024] f16x2
    UIN* __restrict__ hB16)        // [9][32][1024] f16x2
{
    __shared__ float smem[8192];
    float* sA = smem;          // 4096
    float* sB = smem + 4096;   // 4096
    const int bf = detect_bf(IndDet);
    const int tid = threadIdx.x;
    const int bid = blockIdx.x;
    const int tx = tid & 15, ty = tid >> 4;
    const int nbase = (bid & 15) * 64;
    const int by = bid >> 4;   // 0..17
    int t, rb;
    const void* Wsrc;
    const void* bias;
    UIN* dst;
    if (by < 8)        { t = by;     rb = 0;  Wsrc = W1m; bias = nullptr; dst = hA16 + by * 32768; }
    else if (by < 16)  { t = by - 8; rb = 64; Wsrc = W1m; bias = b1m;     dst = hB16 + (by - 8) * 32768; }
    else if (by == 16) { t = 7;      rb = 0;  Wsrc = W1s; bias = nullptr; dst = hA16 + 8 * 32768; }
    else               { t = 7;      rb = 64; Wsrc = W1s; bias = b1s;     dst = hB16 + 8 * 32768; }

    {   // stage x tile -> sA[d][n] (transpose on LDS write)
        const int n_l = tid >> 2, dq = tid & 3;
        const long base = (long)(nbase + n_l) * 512 + t * 64 + dq * 16;
        #pragma unroll
        for (int j = 0; j < 4; ++j) {
            float o[4]; ld4(x, base + j * 4, bf, o);
            const int d0 = dq * 16 + j * 4;
            #pragma unroll
            for (int e = 0; e < 4; ++e) sA[(d0 + e) * 64 + n_l] = o[e];
        }
    }
    {   // stage W tile -> sB[d][c]
        const int d_l = tid >> 2, cq = tid & 3;
        const long base = (long)(rb + d_l) * 64 + cq * 16;
        #pragma unroll
        for (int j = 0; j < 4; ++j) {
            float o[4]; ld4(Wsrc, base + j * 4, bf, o);
            const int c0 = cq * 16 + j * 4;
            #pragma unroll
            for (int e = 0; e < 4; ++e) sB[d_l * 64 + c0 + e] = o[e];
        }
    }
    __syncthreads();

    const int c0 = tx * 4, nq = ty * 4;
    float acc[4][4] = {};  // [ci][ni]
    #pragma unroll 16
    for (int d = 0; d < 64; ++d) {
        const float4 xa = *(const float4*)&sA[d * 64 + nq];
        const float4 wv = *(const float4*)&sB[d * 64 + c0];
        const float aa[4] = {xa.x, xa.y, xa.z, xa.w};
        const float ww[4] = {wv.x, wv.y, wv.z, wv.w};
        #pragma unroll
        for (int ci = 0; ci < 4; ++ci)
            #pragma unroll
            for (int ni = 0; ni < 4; ++ni)
                acc[ci][ni] += ww[ci] * aa[ni];
    }
    float b[4] = {0.f, 0.f, 0.f, 0.f};
    if (bias) {
        #pragma unroll
        for (int ci = 0; ci < 4; ++ci) b[ci] = ldf(bias, c0 + ci, bf);
    }
    const int cp0 = c0 >> 1;   // even
    #pragma unroll
    for (int ni = 0; ni < 4; ++ni) {
        const int col = nbase + nq + ni;
        dst[cp0 * 1024 + col]       = pkh2(acc[0][ni] + b[0], acc[1][ni] + b[1]);
        dst[(cp0 + 1) * 1024 + col] = pkh2(acc[2][ni] + b[2], acc[3][ni] + b[3]);
    }
}

// ---------------------------------------------------------------------------
// Kernel 2: wave-synchronous, MFMA-epilogue. 64-thread blocks (1 wave),
// 16n x 16m per wave; lane owns n0=(lane>>4)*4..+3 rows x m0=lane&15 col
// (== mfma_f32_16x16x32_bf16 C-layout). Grid (64,64) = 4096 waves, zero
// barriers. A_nobs's D_k tile computed by MFMA from E in the epilogue.
// ---------------------------------------------------------------------------
__global__ __launch_bounds__(64) void k_main(
    const UIN* __restrict__ hA16,   // [9][32][1024]
    const UIN* __restrict__ hB16,   // [9][32][1024]
    const void* __restrict__ E,     // [8][1024][64]
    const void* __restrict__ Ind, const void* __restrict__ Loc,
    const void* __restrict__ a, const void* __restrict__ W2m,
    const void* __restrict__ b2m, const void* __restrict__ W2s,
    const void* __restrict__ b2s, const void* __restrict__ g,
    void* __restrict__ out)
{
    __shared__ UIN As[512];       // [32 cp][16 n] f16x2, 2 KB
    __shared__ UIN Bs[512];       // [32 cp][16 m] f16x2, 2 KB
    __shared__ UIN w2m16[32];     // [cp] f16x2
    __shared__ UIN w2s16[256];    // [cp][k] f16x2 (pair over c)
    __shared__ float asoft_l[8];

    const int bf = detect_bf(Ind);
    const int tid = threadIdx.x;   // 0..63 == lane
    const int mb = blockIdx.x * 16, nb = blockIdx.y * 16;
    const int m0 = tid & 15;            // single m col
    const int n0 = (tid >> 4) * 4;      // 4 n rows

    // -- weight staging (wave-synchronous; in-order LDS, no barrier) --
    if (tid < 32) w2m16[tid] = pkh2(ldf(W2m, 2 * tid, bf), ldf(W2m, 2 * tid + 1, bf));
    {   // w2s: 64 threads x 4 entries = 256
        const int cp = tid >> 1, kh = (tid & 1) * 4;
        #pragma unroll
        for (int e = 0; e < 4; ++e) {
            const int k = kh + e;
            w2s16[cp * 8 + k] = pkh2(ldf(W2s, (2 * cp) * 8 + k, bf),
                                     ldf(W2s, (2 * cp + 1) * 8 + k, bf));
        }
    }
    if (tid < 8) {
        float av[8], mx = -1e30f, s = 0.0f;
        #pragma unroll
        for (int k = 0; k < 8; ++k) { av[k] = ldf(a, k, bf); mx = fmaxf(mx, av[k]); }
        #pragma unroll
        for (int k = 0; k < 8; ++k) s += __expf(av[k] - mx);
        asoft_l[tid] = __expf(av[tid] - mx) / s;
    }
    const float b2m_f = ldf(b2m, 0, bf);

    // -- staging map: 2 threads per cp row; each thread 8 consecutive u32 --
    const int cpS = tid >> 1, half = tid & 1;
    const int offA = cpS * 1024 + nb + half * 8;   // u32 idx in plane
    const int offB = cpS * 1024 + mb + half * 8;
    const int ldsS = cpS * 16 + half * 8;          // u32 idx in tile

    // -- initial stage: plane 0 --
    {
        const uint4 a0 = *(const uint4*)(hA16 + offA);
        const uint4 a1 = *(const uint4*)(hA16 + offA + 4);
        const uint4 b0 = *(const uint4*)(hB16 + offB);
        const uint4 b1 = *(const uint4*)(hB16 + offB + 4);
        *(uint4*)&As[ldsS] = a0; *(uint4*)&As[ldsS + 4] = a1;
        *(uint4*)&Bs[ldsS] = b0; *(uint4*)&Bs[ldsS + 4] = b1;
    }

    float amk[4] = {0.f, 0.f, 0.f, 0.f};   // [r] — rows n0..n0+3 at col m0

    // ---- Section A: A_mkt over 8 time steps (no barriers) ----
    for (int t = 0; t < 8; ++t) {
        // prefetch t+1 to regs (t=7 stages plane 8 = section-B tile)
        const uint4 pa0 = *(const uint4*)(hA16 + (t + 1) * 32768 + offA);
        const uint4 pa1 = *(const uint4*)(hA16 + (t + 1) * 32768 + offA + 4);
        const uint4 pb0 = *(const uint4*)(hB16 + (t + 1) * 32768 + offB);
        const uint4 pb1 = *(const uint4*)(hB16 + (t + 1) * 32768 + offB + 4);

        float acc[4] = {0.f, 0.f, 0.f, 0.f};
        #pragma unroll
        for (int cp = 0; cp < 32; ++cp) {
            const uint4 au = *(const uint4*)&As[(cp << 4) + n0];  // 4 rows, broadcast
            const UIN bu = Bs[(cp << 4) + m0];
            const h2 wv = u2h(w2m16[cp]);
            const h2 hb = u2h(bu);
            const h2 z0 = relu2h(u2h(au.x) + hb);
            const h2 z1 = relu2h(u2h(au.y) + hb);
            const h2 z2 = relu2h(u2h(au.z) + hb);
            const h2 z3 = relu2h(u2h(au.w) + hb);
            acc[0] = fdot2(z0, wv, acc[0]);
            acc[1] = fdot2(z1, wv, acc[1]);
            acc[2] = fdot2(z2, wv, acc[2]);
            acc[3] = fdot2(z3, wv, acc[3]);
        }
        const float as_t = asoft_l[t];
        #pragma unroll
        for (int r = 0; r < 4; ++r)
            amk[r] += fmaxf(acc[r] + b2m_f, 0.f) * as_t;

        // overwrite tile with plane t+1 (in-order LDS within the wave)
        *(uint4*)&As[ldsS] = pa0; *(uint4*)&As[ldsS + 4] = pa1;
        *(uint4*)&Bs[ldsS] = pb0; *(uint4*)&Bs[ldsS + 4] = pb1;
    }

    // ---- Section B: logits (plane 8 now in As/Bs) ----
    float lg[4][8];   // [r][k]
    #pragma unroll
    for (int r = 0; r < 4; ++r)
        #pragma unroll
        for (int k = 0; k < 8; ++k) lg[r][k] = 0.f;

    #pragma unroll 8
    for (int cp = 0; cp < 32; ++cp) {
        const uint4 au = *(const uint4*)&As[(cp << 4) + n0];
        const UIN bu = Bs[(cp << 4) + m0];
        const h2 hb = u2h(bu);
        const h2 z[4] = {relu2h(u2h(au.x) + hb), relu2h(u2h(au.y) + hb),
                         relu2h(u2h(au.z) + hb), relu2h(u2h(au.w) + hb)};
        const uint4 wa = *(const uint4*)&w2s16[cp * 8];
        const uint4 wb = *(const uint4*)&w2s16[cp * 8 + 4];
        const UIN wks[8] = {wa.x, wa.y, wa.z, wa.w, wb.x, wb.y, wb.z, wb.w};
        #pragma unroll
        for (int k = 0; k < 8; ++k) {
            const h2 wv = u2h(wks[k]);
            #pragma unroll
            for (int r = 0; r < 4; ++r)
                lg[r][k] = fdot2(z[r], wv, lg[r][k]);
        }
    }

    // ---- Epilogue ----
    float b2s_f[8];
    #pragma unroll
    for (int k = 0; k < 8; ++k) b2s_f[k] = ldf(b2s, k, bf);

    // e[r][k] = exp(relu(lg+b2s) + g), sden[r] = sum_k e
    float e[4][8], sden[4];
    #pragma unroll
    for (int r = 0; r < 4; ++r) {
        const long rowoff = (long)(nb + n0 + r) * 1024 + mb + m0;
        float gv[8];
        ld4(g, rowoff * 8 + 0, bf, gv + 0);
        ld4(g, rowoff * 8 + 4, bf, gv + 4);
        float s = 0.f;
        #pragma unroll
        for (int k = 0; k < 8; ++k) {
            const float l = fmaxf(lg[r][k] + b2s_f[k], 0.f);
            const float ee = __expf(l + gv[k]);
            e[r][k] = ee; s += ee;
        }
        sden[r] = s;
    }

    // D_k tile by MFMA from E (frag layout HW-validated R3-R5):
    // A row / B col = lane&15, k-group = lane>>4; D: col=lane&15,
    // row=(lane>>4)*4+reg == exactly this lane's (n0+r, m0) elements.
    const int fr_ = tid & 15, kg_ = tid >> 4;
    const long an = (long)(nb + fr_) * 64 + kg_ * 8;   // n-side row offset
    const long am = (long)(mb + fr_) * 64 + kg_ * 8;   // m-side row offset
    float dacc[4] = {0.f, 0.f, 0.f, 0.f};
    #pragma unroll 2
    for (int k = 0; k < 8; ++k) {
        const long ek = (long)k << 16;   // k * 65536 elements
        const bfrag af0 = ldfragE(E, ek + an, bf);
        const bfrag af1 = ldfragE(E, ek + an + 32, bf);
        const bfrag bf0 = ldfragE(E, ek + am, bf);
        const bfrag bf1 = ldfragE(E, ek + am + 32, bf);
        f32x4 dk = {};
        dk = __builtin_amdgcn_mfma_f32_16x16x32_bf16(af0, bf0, dk, 0, 0, 0);
        dk = __builtin_amdgcn_mfma_f32_16x16x32_bf16(af1, bf1, dk, 0, 0, 0);
        #pragma unroll
        for (int r = 0; r < 4; ++r)
            dacc[r] += dk[r] * e[r][k];
    }

    // ---- stores ----
    #pragma unroll
    for (int r = 0; r < 4; ++r) {
        const long rowoff = (long)(nb + n0 + r) * 1024 + mb + m0;
        const float nobs = dacc[r] / sden[r];
        if (bf) {
            USH* o = (USH*)out;
            o[rowoff] = ((const USH*)Ind)[rowoff];
            o[1048576 + rowoff] = ((const USH*)Loc)[rowoff];
            o[2 * 1048576 + rowoff] = f2bf(amk[r]);
            o[3 * 1048576 + rowoff] = f2bf(nobs);
        } else {
            float* o = (float*)out;
            o[rowoff] = ((const float*)Ind)[rowoff];
            o[1048576 + rowoff] = ((const float*)Loc)[rowoff];
            o[2 * 1048576 + rowoff] = amk[r];
            o[3 * 1048576 + rowoff] = nobs;
        }
    }
}

extern "C" void kernel_launch(void* const* d_in, const int* in_sizes, int n_in,
                              void* d_out, int out_size, void* d_ws, size_t ws_size,
                              hipStream_t stream) {
    const void* x   = d_in[0];
    const void* Ind = d_in[1];
    const void* Loc = d_in[2];
    const void* a   = d_in[3];
    const void* W1m = d_in[4];
    const void* b1m = d_in[5];
    const void* W2m = d_in[6];
    const void* b2m = d_in[7];
    const void* W1s = d_in[8];
    const void* b1s = d_in[9];
    const void* W2s = d_in[10];
    const void* b2s = d_in[11];
    const void* E   = d_in[12];
    const void* g   = d_in[13];

    UIN* ws   = (UIN*)d_ws;
    UIN* hA16 = ws;                    // [9][32][1024] u32, 1.125 MB
    UIN* hB16 = hA16 + 294912;         // 1.125 MB

    k_pre_d<<<dim3(288), 256, 0, stream>>>(x, W1m, b1m, W1s, b1s, Ind,
                                           hA16, hB16);
    k_main<<<dim3(64, 64), 64, 0, stream>>>(hA16, hB16, E,
                                            Ind, Loc, a, W2m, b2m, W2s, b2s,
                                            g, d_out);
}